// Round 9
// baseline (160.109 us; speedup 1.0000x reference)
//
#include <hip/hip_runtime.h>
#include <hip/hip_bf16.h>
#include <cstdint>
#include <cstddef>

// LSTMCell: gates = [input|hx] @ [Wih|Whh]^T + b_ih + b_hh  (4096 x 4096 x K=2048)
// Round 9: single-product f16 GEMM (absmax 0.051 verified R8), ONE barrier per
// K-step: {stage -> reads(grouped) -> lgkm(4) -> 16 MFMA -> lgkm(0) -> 16 MFMA ->
// vmcnt(4) -> barrier}. 3-sub-buffer ring, distance-2 prefetch, counted vmcnt.
// Ring safety: spre last read at t-1; every wave's t-1 reads done at its lgkmcnt(0)
// before it reaches the step-start barrier -> stage-after-barrier is WAR-safe.

#define B_ROWS 4096
#define HDIM   1024
#define KDIM   2048
#define BM     256
#define BK     32
#define T_STEPS (KDIM / BK)   // 64

typedef unsigned short u16;
using f32x4  = __attribute__((ext_vector_type(4))) float;
using short8 = __attribute__((ext_vector_type(8))) short;
using half8  = __attribute__((ext_vector_type(8))) _Float16;

__device__ __forceinline__ u16 f2h_bits(float f) {
    _Float16 h = (_Float16)f;                    // v_cvt_f16_f32, RTN
    return __builtin_bit_cast(u16, h);
}

// ---------------- pack: f32 -> f16, concat K-dim ----------------
__global__ void pack_kernel(const float* __restrict__ input, const float* __restrict__ hx,
                            const float* __restrict__ wih, const float* __restrict__ whh,
                            u16* __restrict__ Af, u16* __restrict__ Wf)
{
    const int PER = (B_ROWS * KDIM) / 4;  // float4 groups per matrix
    int stride = gridDim.x * blockDim.x;
    for (int i = blockIdx.x * blockDim.x + threadIdx.x; i < 2 * PER; i += stride) {
        int isW = (i >= PER) ? 1 : 0;
        int e = i - isW * PER;
        int row = e >> 9;            // 512 float4-groups per row of 2048
        int k = (e & 511) << 2;
        const float* s0 = isW ? wih : input;
        const float* s1 = isW ? whh : hx;
        const float* src = (k < 1024) ? (s0 + (size_t)row * 1024 + k)
                                      : (s1 + (size_t)row * 1024 + (k - 1024));
        float4 v = *(const float4*)src;
        size_t doff = (size_t)row * KDIM + k;
        u16* dst = (isW ? Wf : Af) + doff;
        *(ushort4*)dst = make_ushort4(f2h_bits(v.x), f2h_bits(v.y),
                                      f2h_bits(v.z), f2h_bits(v.w));
    }
}

// ---------------- fused GEMM + LSTM epilogue ----------------
__device__ __forceinline__ void gload16(const void* g, void* l) {
    __builtin_amdgcn_global_load_lds((const __attribute__((address_space(1))) void*)g,
                                     (__attribute__((address_space(3))) void*)l, 16, 0, 0);
}
__device__ __forceinline__ float sigmf(float x) { return 1.0f / (1.0f + __expf(-x)); }
__device__ __forceinline__ float tanhfast(float x) { return 1.0f - 2.0f / (1.0f + __expf(2.0f * x)); }

__launch_bounds__(512, 2)
__global__ void lstm_fused(const u16* __restrict__ Afp, const u16* __restrict__ Wfp,
                           const float* __restrict__ cx, const float* __restrict__ eps_c,
                           const float* __restrict__ eps_h,
                           const float* __restrict__ bias_ih, const float* __restrict__ bias_hh,
                           const float* __restrict__ noise_q, const float* __restrict__ noise_e,
                           float* __restrict__ out)
{
    // k-chunk-panel layout [sb(3)][kc(4)][row(256)][8] u16 — linear for global_load_lds,
    // conflict-free ds_read_b128 (0 conflicts measured R1-R8). 3 x 16 KB x 2 tiles = 96 KB.
    __shared__ __align__(16) u16 lA[3][4][256][8];
    __shared__ __align__(16) u16 lW[3][4][256][8];

    int bid = blockIdx.x;
    // XCD-bijective swizzle (256 % 8 == 0): XCD x gets w in [32x,32x+32) -> 2 hq
    // values (W working set 2 MB, L2-resident) x all 16 A panels.
    int w = (bid & 7) * 32 + (bid >> 3);
    int mi = w & 15;          // 16 M-chunks of 256 rows
    int hq = w >> 4;          // 16 h-chunks of 64 cols (x4 gates = 256 gate-cols)
    int bm0 = mi * BM;
    int h0 = hq * 64;

    int tid  = threadIdx.x;
    int lane = tid & 63;
    int wid  = tid >> 6;      // 0..7
    int wm   = wid >> 2;      // M half (128 rows)
    int wn   = wid & 3;       // h quarter (16 cols x 4 gates = 64 gate-cols)

    // ---- staging mapping: thread -> (row = tid&255, kc base = tid>>8), 2 loads kc,kc+2 ----
    int rSt = tid & 255;
    int kS  = tid >> 8;       // 0/1
    const u16* Asrc = Afp + (size_t)(bm0 + rSt) * KDIM;
    // LDS W row n <-> global gate row: gate = n>>6, h = h0 + (n&63)
    int wgrow = (rSt >> 6) * 1024 + h0 + (rSt & 63);
    const u16* Wsrc = Wfp + (size_t)wgrow * KDIM;

#define STG_A(sb, t_) do { \
        gload16(Asrc + (t_) * 32 + kS * 8,       &lA[sb][kS][rSt][0]);     \
        gload16(Asrc + (t_) * 32 + (kS + 2) * 8, &lA[sb][kS + 2][rSt][0]); } while (0)
#define STG_W(sb, t_) do { \
        gload16(Wsrc + (t_) * 32 + kS * 8,       &lW[sb][kS][rSt][0]);     \
        gload16(Wsrc + (t_) * 32 + (kS + 2) * 8, &lW[sb][kS + 2][rSt][0]); } while (0)

    // ---- fragment read indices ----
    int fk = lane >> 4, fr = lane & 15;

    f32x4 acc[8][4];   // [m-frag][gate]
#pragma unroll
    for (int m = 0; m < 8; ++m)
#pragma unroll
        for (int g = 0; g < 4; ++g)
            acc[m][g] = (f32x4){0.f, 0.f, 0.f, 0.f};

    // ---- prologue: stage steps 0,1 into sb0,sb1; wait only sb0 (4 newest in flight) ----
    STG_A(0, 0); STG_W(0, 0);
    STG_A(1, 1); STG_W(1, 1);
    asm volatile("s_waitcnt vmcnt(4)");
    __builtin_amdgcn_s_barrier();

#define LD8(p) __builtin_bit_cast(half8, *(const short8*)(p))
#define SB0()  __builtin_amdgcn_sched_barrier(0)

#define MFMA8(mb, AX, AY) do { \
        _Pragma("unroll") \
        for (int g = 0; g < 4; ++g) { \
            acc[(mb)][g]     = __builtin_amdgcn_mfma_f32_16x16x32_f16(AX, wf[g], acc[(mb)][g], 0, 0, 0); \
            acc[(mb) + 1][g] = __builtin_amdgcn_mfma_f32_16x16x32_f16(AY, wf[g], acc[(mb) + 1][g], 0, 0, 0); \
        } \
    } while (0)

#pragma unroll 1
    for (int t = 0; t < T_STEPS; ++t) {
        const int scur = t % 3;
        const int spre = (t + 2) % 3;
        const bool pre = (t < T_STEPS - 2);
        const u16* pA = &lA[scur][fk][wm * 128 + fr][0];
        const u16* pW = &lW[scur][fk][wn * 16 + fr][0];

        half8 wf[4], a0, a1, a2, a3, a4, a5, a6, a7;

        SB0();   // pin everything below the step-start barrier
        // ---- stage t+2 (vmcnt ops; long latency, overlaps everything) ----
        if (pre) { STG_A(spre, t + 2); STG_W(spre, t + 2); }
        // ---- group 1: the 8 reads MFMA-A needs ----
        wf[0] = LD8(pW);        wf[1] = LD8(pW + 512);
        wf[2] = LD8(pW + 1024); wf[3] = LD8(pW + 1536);
        a0 = LD8(pA);           a1 = LD8(pA + 128);
        a2 = LD8(pA + 256);     a3 = LD8(pA + 384);
        SB0();   // group boundary: the 8 above are the first-issued ds ops
        // ---- group 2: the 4 reads MFMA-B needs ----
        a4 = LD8(pA + 512);     a5 = LD8(pA + 640);
        a6 = LD8(pA + 768);     a7 = LD8(pA + 896);
        SB0();
        asm volatile("s_waitcnt lgkmcnt(4)");   // group 1 done; group 2 may be in flight
        SB0();
        __builtin_amdgcn_s_setprio(1);
        MFMA8(0, a0, a1);
        MFMA8(2, a2, a3);
        __builtin_amdgcn_s_setprio(0);
        SB0();
        asm volatile("s_waitcnt lgkmcnt(0)");   // group 2 done (overlapped MFMA-A)
        SB0();
        __builtin_amdgcn_s_setprio(1);
        MFMA8(4, a4, a5);
        MFMA8(6, a6, a7);
        __builtin_amdgcn_s_setprio(0);
        SB0();
        if (pre) asm volatile("s_waitcnt vmcnt(4)");   // t+1's loads landed; t+2's in flight
        else     asm volatile("s_waitcnt vmcnt(0)");
        __builtin_amdgcn_s_barrier();           // single barrier per step
    }

    // ---- epilogue: all 4 gates for (r,h) are lane-local ----
    float sq_e = sqrtf(noise_e[0]);
    float sq_q = sqrtf(noise_q[0]);
    int h = h0 + wn * 16 + fr;
    float bsum[4];
#pragma unroll
    for (int g = 0; g < 4; ++g)
        bsum[g] = bias_ih[g * 1024 + h] + bias_hh[g * 1024 + h];
#pragma unroll
    for (int m = 0; m < 8; ++m) {
        int r0 = bm0 + wm * 128 + m * 16 + fk * 4;
#pragma unroll
        for (int j = 0; j < 4; ++j) {
            int r = r0 + j;
            float gi = acc[m][0][j] + bsum[0];
            float gf = acc[m][1][j] + bsum[1];
            float gc = acc[m][2][j] + bsum[2];
            float go = acc[m][3][j] + bsum[3];
            float ig = sigmf(gi), fg = sigmf(gf);
            float cg = tanhfast(gc), og = sigmf(go);
            size_t off = (size_t)r * HDIM + h;
            float cyv = fg * cx[off] + ig * cg + sq_e * eps_c[off];
            float hyv = og * tanhfast(cyv) + sq_q * eps_h[off];
            out[off] = hyv;                                 // hy
            out[(size_t)B_ROWS * HDIM + off] = cyv;         // cy
        }
    }
}

extern "C" void kernel_launch(void* const* d_in, const int* in_sizes, int n_in,
                              void* d_out, int out_size, void* d_ws, size_t ws_size,
                              hipStream_t stream)
{
    const float* input = (const float*)d_in[0];
    const float* hx    = (const float*)d_in[1];
    const float* cx    = (const float*)d_in[2];
    const float* nq    = (const float*)d_in[3];
    const float* ne    = (const float*)d_in[4];
    const float* wih   = (const float*)d_in[5];
    const float* whh   = (const float*)d_in[6];
    const float* bih   = (const float*)d_in[7];
    const float* bhh   = (const float*)d_in[8];
    const float* epsc  = (const float*)d_in[9];
    const float* epsh  = (const float*)d_in[10];
    float* out = (float*)d_out;

    u16* Af = (u16*)d_ws;
    u16* Wf = Af + (size_t)B_ROWS * KDIM;   // 32 MB of ws total

    hipLaunchKernelGGL(pack_kernel, dim3(2048), dim3(256), 0, stream,
                       input, hx, wih, whh, Af, Wf);
    hipLaunchKernelGGL(lstm_fused, dim3(256), dim3(512), 0, stream,
                       Af, Wf, cx, epsc, epsh, bih, bhh, nq, ne, out);
}

// Round 10
// 155.608 us; speedup vs baseline: 1.0289x; 1.0289x over previous
//
#include <hip/hip_runtime.h>
#include <hip/hip_bf16.h>
#include <cstdint>
#include <cstddef>

// LSTMCell: gates = [input|hx] @ [Wih|Whh]^T + b_ih + b_hh  (4096 x 4096 x K=2048)
// Round 10: single-product f16 GEMM (absmax 0.051 verified R8/R9) with R8's exact
// 2-phase protocol scaled to BK=64 + double-buffer (128 KB LDS): half the sync
// events per K. Phase A: stage 8 gloads(t+1) || read W(k0,k1)+A m0-3 -> bar ->
// lgkm0 -> 32 MFMA -> bar. Phase B: read A m4-7 -> bar -> lgkm0 -> 32 MFMA ->
// vmcnt(0) (loads issued ~2500cyc earlier) -> bar.

#define B_ROWS 4096
#define HDIM   1024
#define KDIM   2048
#define BM     256
#define BK     64
#define T_STEPS (KDIM / BK)   // 32

typedef unsigned short u16;
using f32x4  = __attribute__((ext_vector_type(4))) float;
using short8 = __attribute__((ext_vector_type(8))) short;
using half8  = __attribute__((ext_vector_type(8))) _Float16;

__device__ __forceinline__ u16 f2h_bits(float f) {
    _Float16 h = (_Float16)f;                    // v_cvt_f16_f32, RTN
    return __builtin_bit_cast(u16, h);
}

// ---------------- pack: f32 -> f16, concat K-dim ----------------
__global__ void pack_kernel(const float* __restrict__ input, const float* __restrict__ hx,
                            const float* __restrict__ wih, const float* __restrict__ whh,
                            u16* __restrict__ Af, u16* __restrict__ Wf)
{
    const int PER = (B_ROWS * KDIM) / 4;  // float4 groups per matrix
    int stride = gridDim.x * blockDim.x;
    for (int i = blockIdx.x * blockDim.x + threadIdx.x; i < 2 * PER; i += stride) {
        int isW = (i >= PER) ? 1 : 0;
        int e = i - isW * PER;
        int row = e >> 9;            // 512 float4-groups per row of 2048
        int k = (e & 511) << 2;
        const float* s0 = isW ? wih : input;
        const float* s1 = isW ? whh : hx;
        const float* src = (k < 1024) ? (s0 + (size_t)row * 1024 + k)
                                      : (s1 + (size_t)row * 1024 + (k - 1024));
        float4 v = *(const float4*)src;
        size_t doff = (size_t)row * KDIM + k;
        u16* dst = (isW ? Wf : Af) + doff;
        *(ushort4*)dst = make_ushort4(f2h_bits(v.x), f2h_bits(v.y),
                                      f2h_bits(v.z), f2h_bits(v.w));
    }
}

// ---------------- fused GEMM + LSTM epilogue ----------------
__device__ __forceinline__ void gload16(const void* g, void* l) {
    __builtin_amdgcn_global_load_lds((const __attribute__((address_space(1))) void*)g,
                                     (__attribute__((address_space(3))) void*)l, 16, 0, 0);
}
__device__ __forceinline__ float sigmf(float x) { return 1.0f / (1.0f + __expf(-x)); }
__device__ __forceinline__ float tanhfast(float x) { return 1.0f - 2.0f / (1.0f + __expf(2.0f * x)); }

__launch_bounds__(512, 2)
__global__ void lstm_fused(const u16* __restrict__ Afp, const u16* __restrict__ Wfp,
                           const float* __restrict__ cx, const float* __restrict__ eps_c,
                           const float* __restrict__ eps_h,
                           const float* __restrict__ bias_ih, const float* __restrict__ bias_hh,
                           const float* __restrict__ noise_q, const float* __restrict__ noise_e,
                           float* __restrict__ out)
{
    // k-chunk-panel layout [buf(2)][kc(8)][row(256)][8] u16 — linear for
    // global_load_lds, conflict-free ds_read_b128 (0 conflicts R1-R9). 2x32KB x2 = 128 KB.
    __shared__ __align__(16) u16 lA[2][8][256][8];
    __shared__ __align__(16) u16 lW[2][8][256][8];

    int bid = blockIdx.x;
    // XCD-bijective swizzle (256 % 8 == 0): XCD x gets w in [32x,32x+32) -> 2 hq
    // values (W working set 2 MB, L2-resident) x all 16 A panels.
    int w = (bid & 7) * 32 + (bid >> 3);
    int mi = w & 15;          // 16 M-chunks of 256 rows
    int hq = w >> 4;          // 16 h-chunks of 64 cols (x4 gates = 256 gate-cols)
    int bm0 = mi * BM;
    int h0 = hq * 64;

    int tid  = threadIdx.x;
    int lane = tid & 63;
    int wid  = tid >> 6;      // 0..7
    int wm   = wid >> 2;      // M half (128 rows)
    int wn   = wid & 3;       // h quarter (16 cols x 4 gates = 64 gate-cols)

    // ---- staging mapping: thread -> (row = tid&255, kc parity = tid>>8), kc = kS+2s ----
    int rSt = tid & 255;
    int kS  = tid >> 8;       // 0/1
    const u16* Asrc = Afp + (size_t)(bm0 + rSt) * KDIM;
    // LDS W row n <-> global gate row: gate = n>>6, h = h0 + (n&63)
    int wgrow = (rSt >> 6) * 1024 + h0 + (rSt & 63);
    const u16* Wsrc = Wfp + (size_t)wgrow * KDIM;

#define STG_A(b, t_) do { \
        _Pragma("unroll") \
        for (int s = 0; s < 4; ++s) { \
            int kc = kS + 2 * s; \
            gload16(Asrc + (t_) * 64 + kc * 8, &lA[b][kc][rSt][0]); \
        } } while (0)
#define STG_W(b, t_) do { \
        _Pragma("unroll") \
        for (int s = 0; s < 4; ++s) { \
            int kc = kS + 2 * s; \
            gload16(Wsrc + (t_) * 64 + kc * 8, &lW[b][kc][rSt][0]); \
        } } while (0)

    // ---- fragment read indices ----
    int fk = lane >> 4, fr = lane & 15;
    // element strides in lA/lW: buf 16384, kc 2048, row 8
    const u16* pAbase = &lA[0][0][0][0] + fk * 2048 + (wm * 128 + fr) * 8;
    const u16* pWbase = &lW[0][0][0][0] + fk * 2048 + (wn * 16 + fr) * 8;

    f32x4 acc[8][4];   // [m-frag][gate]
#pragma unroll
    for (int m = 0; m < 8; ++m)
#pragma unroll
        for (int g = 0; g < 4; ++g)
            acc[m][g] = (f32x4){0.f, 0.f, 0.f, 0.f};

    // ---- prologue: stage step 0 into buf0, drain, barrier ----
    STG_A(0, 0); STG_W(0, 0);
    asm volatile("s_waitcnt vmcnt(0)");
    __builtin_amdgcn_s_barrier();

#define LD8(p) __builtin_bit_cast(half8, *(const short8*)(p))

#define MFMA16(mb, A0, A1, A2, A3, WF) do { \
        _Pragma("unroll") \
        for (int g = 0; g < 4; ++g) { \
            acc[(mb)][g]     = __builtin_amdgcn_mfma_f32_16x16x32_f16(A0, WF[g], acc[(mb)][g], 0, 0, 0); \
            acc[(mb) + 1][g] = __builtin_amdgcn_mfma_f32_16x16x32_f16(A1, WF[g], acc[(mb) + 1][g], 0, 0, 0); \
        } \
        _Pragma("unroll") \
        for (int g = 0; g < 4; ++g) { \
            acc[(mb) + 2][g] = __builtin_amdgcn_mfma_f32_16x16x32_f16(A2, WF[g], acc[(mb) + 2][g], 0, 0, 0); \
            acc[(mb) + 3][g] = __builtin_amdgcn_mfma_f32_16x16x32_f16(A3, WF[g], acc[(mb) + 3][g], 0, 0, 0); \
        } \
    } while (0)

#define WAIT_LGKM() do { \
        asm volatile("s_waitcnt lgkmcnt(0)"); \
        __builtin_amdgcn_sched_barrier(0); \
    } while (0)

#pragma unroll 1
    for (int t = 0; t < T_STEPS; ++t) {
        const int cur = t & 1;
        const bool pre = (t < T_STEPS - 1);
        const u16* pA = pAbase + cur * 16384;   // ksub0; ksub1 at +8192
        const u16* pW = pWbase + cur * 16384;

        half8 wf0[4], wf1[4];
        half8 a0, a1, a2, a3, b0, b1, b2, b3;

        // ---- Phase A: stage ALL of t+1 ; read W(k0,k1) + A m0..3(k0,k1) ----
        if (pre) { STG_A(cur ^ 1, t + 1); STG_W(cur ^ 1, t + 1); }
#pragma unroll
        for (int g = 0; g < 4; ++g) {
            wf0[g] = LD8(pW + g * 512);
            wf1[g] = LD8(pW + 8192 + g * 512);
        }
        a0 = LD8(pA);           a1 = LD8(pA + 128);
        a2 = LD8(pA + 256);     a3 = LD8(pA + 384);
        b0 = LD8(pA + 8192);        b1 = LD8(pA + 8192 + 128);
        b2 = LD8(pA + 8192 + 256);  b3 = LD8(pA + 8192 + 384);
        __builtin_amdgcn_s_barrier();
        WAIT_LGKM();
        __builtin_amdgcn_s_setprio(1);
        MFMA16(0, a0, a1, a2, a3, wf0);     // m0-3, ksub0
        MFMA16(0, b0, b1, b2, b3, wf1);     // m0-3, ksub1
        __builtin_amdgcn_s_setprio(0);
        __builtin_amdgcn_s_barrier();

        // ---- Phase B: read A m4..7(k0,k1) ; MFMA ; drain t+1's loads (issued ~2500cyc ago) ----
        a0 = LD8(pA + 512);         a1 = LD8(pA + 640);
        a2 = LD8(pA + 768);         a3 = LD8(pA + 896);
        b0 = LD8(pA + 8192 + 512);  b1 = LD8(pA + 8192 + 640);
        b2 = LD8(pA + 8192 + 768);  b3 = LD8(pA + 8192 + 896);
        __builtin_amdgcn_s_barrier();
        WAIT_LGKM();
        __builtin_amdgcn_s_setprio(1);
        MFMA16(4, a0, a1, a2, a3, wf0);     // m4-7, ksub0
        MFMA16(4, b0, b1, b2, b3, wf1);     // m4-7, ksub1
        __builtin_amdgcn_s_setprio(0);
        asm volatile("s_waitcnt vmcnt(0)");  // t+1's buffer fully landed
        __builtin_amdgcn_s_barrier();
        __builtin_amdgcn_sched_barrier(0);   // pin step boundary
    }

    // ---- epilogue: all 4 gates for (r,h) are lane-local ----
    float sq_e = sqrtf(noise_e[0]);
    float sq_q = sqrtf(noise_q[0]);
    int h = h0 + wn * 16 + fr;
    float bsum[4];
#pragma unroll
    for (int g = 0; g < 4; ++g)
        bsum[g] = bias_ih[g * 1024 + h] + bias_hh[g * 1024 + h];
#pragma unroll
    for (int m = 0; m < 8; ++m) {
        int r0 = bm0 + wm * 128 + m * 16 + fk * 4;
#pragma unroll
        for (int j = 0; j < 4; ++j) {
            int r = r0 + j;
            float gi = acc[m][0][j] + bsum[0];
            float gf = acc[m][1][j] + bsum[1];
            float gc = acc[m][2][j] + bsum[2];
            float go = acc[m][3][j] + bsum[3];
            float ig = sigmf(gi), fg = sigmf(gf);
            float cg = tanhfast(gc), og = sigmf(go);
            size_t off = (size_t)r * HDIM + h;
            float cyv = fg * cx[off] + ig * cg + sq_e * eps_c[off];
            float hyv = og * tanhfast(cyv) + sq_q * eps_h[off];
            out[off] = hyv;                                 // hy
            out[(size_t)B_ROWS * HDIM + off] = cyv;         // cy
        }
    }
}

extern "C" void kernel_launch(void* const* d_in, const int* in_sizes, int n_in,
                              void* d_out, int out_size, void* d_ws, size_t ws_size,
                              hipStream_t stream)
{
    const float* input = (const float*)d_in[0];
    const float* hx    = (const float*)d_in[1];
    const float* cx    = (const float*)d_in[2];
    const float* nq    = (const float*)d_in[3];
    const float* ne    = (const float*)d_in[4];
    const float* wih   = (const float*)d_in[5];
    const float* whh   = (const float*)d_in[6];
    const float* bih   = (const float*)d_in[7];
    const float* bhh   = (const float*)d_in[8];
    const float* epsc  = (const float*)d_in[9];
    const float* epsh  = (const float*)d_in[10];
    float* out = (float*)d_out;

    u16* Af = (u16*)d_ws;
    u16* Wf = Af + (size_t)B_ROWS * KDIM;   // 32 MB of ws total

    hipLaunchKernelGGL(pack_kernel, dim3(2048), dim3(256), 0, stream,
                       input, hx, wih, whh, Af, Wf);
    hipLaunchKernelGGL(lstm_fused, dim3(256), dim3(512), 0, stream,
                       Af, Wf, cx, epsc, epsh, bih, bhh, nq, ne, out);
}